// Round 9
// baseline (77.903 us; speedup 1.0000x reference)
//
#include <hip/hip_runtime.h>

typedef __attribute__((ext_vector_type(8))) short bfrag;   // 8 bf16 = 4 VGPR
typedef __attribute__((ext_vector_type(4))) float f32x4;

namespace {
constexpr int N_ = 16, C_ = 112, H_ = 48, W_ = 48, HW_ = 2304;
constexpr int NKS = 18;  // K-slices of 128 for gram (18*128 = 2304)
// ws float offsets
constexpr int WS_T7 = 0;          // 768
constexpr int WS_T17 = 768;       // 112
constexpr int WS_A = 1024;        // 1792
constexpr int WS_A2 = 2816;       // 16*8 = 128
constexpr int WS_V = 4096;        // 16*112*7 = 12544 -> 16640
constexpr int WS_MX = 16640;      // 16*2304 = 36864 -> 53504
constexpr int WS_WPACK = 53504;   // 3*112*128 bf16 = 21504 f -> 75008
constexpr int WS_GBF = 75008;     // 16*112*128 bf16 = 114688 f -> 189696
constexpr int WS_SPART = 189696;  // 18*16*12544 f32 -> 3802368
constexpr int WS_VP = 3802368;    // 16*18*112*8 = 258048 -> 4060416 (16.2 MB)
}

__device__ __forceinline__ float f4e(const float4& v, int e) {
  return e == 0 ? v.x : e == 1 ? v.y : e == 2 ? v.z : v.w;
}
__device__ __forceinline__ unsigned short f2bf(float f) {  // RNE
  unsigned u = __float_as_uint(f);
  return (unsigned short)((u + 0x7FFFu + ((u >> 16) & 1u)) >> 16);
}
__device__ __forceinline__ float bf2f(unsigned short s) {
  return __uint_as_float(((unsigned)s) << 16);
}

// ---------------------------------------------------------------------------
// K1: Gram via MFMA + fused channel-sum + fused V-buckets (+ wpack tail).
// grid 288+42 linear. Blocks <288: (ks = bid%18, n = bid/18): stage
// x[n,:,k0:k0+128] slab bf16; colsum -> MX; V-part (class = p mod 7, since
// 49 = 0 mod 7) -> VP; 49 16x16 S-tiles -> SPART. Blocks >=288: pack conv
// weights bf16 [kx][o][i pad 128].
__global__ __launch_bounds__(256) void ath_gram(const float* __restrict__ x,
                                                const float* __restrict__ cw,
                                                float* __restrict__ ws) {
  const int bid = blockIdx.x;
  const int tid = threadIdx.x;
  if (bid >= NKS * N_) {  // ---- wpack tail
    int idx = (bid - NKS * N_) * 256 + tid;  // over 3*112*32 quads
    if (idx < 3 * 112 * 32) {
      int kx = idx / (112 * 32);
      int r = idx - kx * 112 * 32;
      int o = r >> 5;
      int i0 = (r & 31) * 4;
      unsigned short v[4];
#pragma unroll
      for (int e = 0; e < 4; ++e) {
        int i = i0 + e;
        v[e] = (i < 112) ? f2bf(cw[o * 336 + i * 3 + kx]) : (unsigned short)0;
      }
      unsigned short* wp = (unsigned short*)(ws + WS_WPACK);
      *(ushort4*)&wp[(kx * 112 + o) * 128 + i0] = make_ushort4(v[0], v[1], v[2], v[3]);
    }
    return;
  }
  const int ks = bid % NKS, n = bid / NKS;
  const int k0 = ks * 128;
  const int lane = tid & 63, wv = tid >> 6;
  const int lr = lane & 15, lg = lane >> 4;
  __shared__ __align__(16) unsigned short xbs[112][136];  // 272B row stride
  __shared__ float4 csred[256];
  const int kq = tid & 31;  // col-quad (16B) 0..31
  const int cg = tid >> 5;  // 0..7
  float4 cs = make_float4(0.f, 0.f, 0.f, 0.f);
#pragma unroll
  for (int r = 0; r < 14; ++r) {
    const int c = cg + 8 * r;
    float4 v = *(const float4*)&x[((size_t)n * C_ + c) * HW_ + k0 + 4 * kq];
    cs.x += v.x; cs.y += v.y; cs.z += v.z; cs.w += v.w;
    *(ushort4*)&xbs[c][4 * kq] =
        make_ushort4(f2bf(v.x), f2bf(v.y), f2bf(v.z), f2bf(v.w));
  }
  csred[tid] = cs;
  __syncthreads();
  if (tid < 32) {
    float4 s = csred[tid];
#pragma unroll
    for (int g = 1; g < 8; ++g) {
      float4 t = csred[tid + 32 * g];
      s.x += t.x; s.y += t.y; s.z += t.z; s.w += t.w;
    }
    *(float4*)&ws[WS_MX + n * HW_ + k0 + 4 * tid] = s;
  }
  // V partials: thread c<112 sums its slab row by residue (k0+j) mod 7 == m
  if (tid < 112) {
    const int c = tid;
    const int k0m7 = k0 % 7;
    float* vp = ws + WS_VP + (size_t)((n * NKS + ks) * 112 + c) * 8;
#pragma unroll
    for (int m = 0; m < 7; ++m) {
      int jm = (m - k0m7 + 7) % 7;
      float s = 0.f;
      for (int j = jm; j < 128; j += 7) s += bf2f(xbs[c][j]);
      vp[m] = s;
    }
  }
  // MFMA: 49 tiles round-robin over 4 waves
  f32x4 acc[13];
#pragma unroll
  for (int j = 0; j < 13; ++j) acc[j] = (f32x4){0.f, 0.f, 0.f, 0.f};
#pragma unroll
  for (int j = 0; j < 13; ++j) {
    int t = wv + 4 * j;
    if (t < 49) {
      int tc = t / 7, ti = t - 7 * tc;
      const unsigned short* arow = &xbs[16 * tc + lr][8 * lg];
      const unsigned short* brow = &xbs[16 * ti + lr][8 * lg];
#pragma unroll
      for (int kb = 0; kb < 4; ++kb) {
        bfrag a = *(const bfrag*)(arow + 32 * kb);
        bfrag b = *(const bfrag*)(brow + 32 * kb);
        acc[j] = __builtin_amdgcn_mfma_f32_16x16x32_bf16(a, b, acc[j], 0, 0, 0);
      }
    }
  }
  float* sp = ws + WS_SPART + (size_t)(n * NKS + ks) * 12544;
#pragma unroll
  for (int j = 0; j < 13; ++j) {
    int t = wv + 4 * j;
    if (t < 49) {
      int tc = t / 7, ti = t - 7 * tc;
#pragma unroll
      for (int e = 0; e < 4; ++e)
        sp[(16 * tc + 4 * lg + e) * C_ + 16 * ti + lr] = acc[j][e];
    }
  }
}

// ---------------------------------------------------------------------------
// K2: per-n finisher. grid N, 128 threads.
// t7 (value from mean-row h' lands at (h'+2)%48), t17, T, A2[r]=sum_h
// t7[h]*D[(r-h)%7], V-reduce over slices.
__global__ __launch_bounds__(128) void ath_t7n(const float* __restrict__ p7,
                                               float* __restrict__ ws) {
  const int n = blockIdx.x;
  const int tid = threadIdx.x;
  __shared__ float mxs[2304];
  __shared__ float t7s[48];
  __shared__ float st17[7];
  for (int idx = tid; idx < HW_; idx += 128)
    mxs[idx] = ws[WS_MX + n * HW_ + idx] * (1.0f / 112.0f);
  // V-reduce (independent of t7 chain)
  if (tid < 112) {
    const int c = tid;
#pragma unroll
    for (int m = 0; m < 7; ++m) {
      float s = 0.f;
      for (int ksi = 0; ksi < NKS; ++ksi)
        s += ws[WS_VP + (size_t)((n * NKS + ksi) * 112 + c) * 8 + m];
      ws[WS_V + ((size_t)n * C_ + c) * 7 + m] = s;
    }
  }
  __syncthreads();
  if (tid < 48) {
    float s = 0.f;
    for (int k = 0; k < 3; ++k)
      for (int wp = 0; wp < W_; ++wp) {
        int j = 3 * k + wp - 3;
        if (j >= 0 && j < W_) s += mxs[tid * 48 + j] * p7[k * W_ + wp];
      }
    const int hd = (tid + 2) % 48;  // S3=+1,S6=+1 rolls compound to +2
    t7s[hd] = s;
    ws[WS_T7 + n * H_ + hd] = s;
  }
  __syncthreads();
  if (tid < 7) {
    float s = 0.f;
    for (int hh = 0; hh < 48; ++hh) {
      int j = 2 * tid + hh - 6;
      if (j >= 0 && j < 48) s += fabsf(t7s[j]);
    }
    st17[tid] = s * (1.0f / 48.0f);
    ws[WS_T17 + n * 7 + tid] = st17[tid];
  }
  __syncthreads();
  if (tid < 7) {
    float T = 0.f;
#pragma unroll
    for (int j = 0; j < 7; ++j) T += st17[j];
    const int r = tid;
    float a2 = 0.f;
    for (int h = 0; h < 48; ++h) {
      int s6 = ((r - h + 6) % 7 + 7) % 7;
      a2 += t7s[h] * (7.f * T - st17[s6]);
    }
    ws[WS_A2 + n * 8 + r] = a2;
  }
}

// ---------------------------------------------------------------------------
// K3: assemble G' -> bf16 Gbf[n][c][i pad 128]; plus A1[n,c] = sum_p x*t7
// and A'[n,c]. grid 224 (14 blocks per n, 8 c's per block), 256 threads.
__global__ __launch_bounds__(256) void ath_assemble(const float* __restrict__ x,
                                                    const float* __restrict__ p19,
                                                    float* __restrict__ ws) {
  const int bid = blockIdx.x;
  const int n = bid / 14, bcl = bid % 14;
  const int tid = threadIdx.x;
  const int q = tid & 31, cloc = tid >> 5;
  const int c = bcl * 8 + cloc;
  __shared__ float t7s[48];
  __shared__ float st17[7];
  __shared__ float sa2[8];
  if (tid < 48) t7s[tid] = ws[WS_T7 + n * H_ + tid];
  if (tid < 7) st17[tid] = ws[WS_T17 + n * 7 + tid];
  if (tid < 8) sa2[tid] = (tid < 7) ? ws[WS_A2 + n * 8 + tid] : 0.f;
  __syncthreads();
  // A1: dot(x[n,c,:], t7[p/48]) spread over the 32 lanes of this c-group
  const float* xr = x + ((size_t)n * C_ + c) * HW_;
  float a1 = 0.f;
#pragma unroll
  for (int t = 0; t < 18; ++t) {
    int p = 4 * q + 128 * t;
    float4 v = *(const float4*)&xr[p];
#pragma unroll
    for (int e = 0; e < 4; ++e) a1 += f4e(v, e) * t7s[(p + e) / 48];
  }
#pragma unroll
  for (int off = 16; off >= 1; off >>= 1) a1 += __shfl_xor(a1, off);
  if (q == 0)
    ws[WS_A + n * C_ + c] = p19[c] * (a1 + sa2[c % 7]) * (2.0f / 48.0f);
  // G' row
  const int i0 = 4 * q;
  unsigned short v[4] = {0, 0, 0, 0};
  if (i0 < 112) {
    float4 s = make_float4(0.f, 0.f, 0.f, 0.f);
    for (int kc = 0; kc < NKS; ++kc) {
      float4 t = *(const float4*)&ws[WS_SPART + (size_t)(n * NKS + kc) * 12544 + c * C_ + i0];
      s.x += t.x; s.y += t.y; s.z += t.z; s.w += t.w;
    }
    const float scale = 1.0f / (48.0f * sqrtf(112.0f));
    const float pc = p19[c];
    int j0 = c % 7;
#pragma unroll
    for (int e = 0; e < 4; ++e) {
      const float* vp = ws + WS_V + ((size_t)n * C_ + i0 + e) * 7;
      float t = 0.f;
#pragma unroll
      for (int m = 0; m < 7; ++m) {
        int jj = j0 + m;
        jj = (jj >= 7) ? jj - 7 : jj;
        t += st17[jj] * vp[m];
      }
      v[e] = f2bf(pc * (f4e(s, e) + t) * scale);
    }
  }
  unsigned short* gb = (unsigned short*)(ws + WS_GBF);
  *(ushort4*)&gb[((size_t)n * C_ + c) * 128 + i0] = make_ushort4(v[0], v[1], v[2], v[3]);
}

// ---------------------------------------------------------------------------
// K4 fused via MFMA. xT[52][136] bf16: row r = w+2 (rows 0,1,50,51 zero);
// cols 112..135 zero (K-pad). conv = 3 shift-GEMMs vs wpack; t13 in-place;
// final GEMM vs Gbf. 21 16x16 tiles round-robin over 4 waves.
__global__ __launch_bounds__(256) void ath_fused(const float* __restrict__ x,
                                                 const float* __restrict__ ws,
                                                 float* __restrict__ out) {
  const int h = blockIdx.x, n = blockIdx.y;
  const int tid = threadIdx.x;
  const int lane = tid & 63, wv = tid >> 6;
  const int lr = lane & 15, lg = lane >> 4;
  __shared__ __align__(16) unsigned short xT[52][136];
  __shared__ float sA[112];
  const float* xb = x + (size_t)n * C_ * HW_ + h * W_;
  for (int idx = tid; idx < 52 * 24; idx += 256) {
    int r2 = idx / 24, cc = 112 + idx % 24;
    xT[r2][cc] = 0;
  }
  for (int idx = tid; idx < 4 * 112; idx += 256) {
    int rr = idx / 112;
    int r2 = (rr < 2) ? rr : 48 + rr;
    xT[r2][idx % 112] = 0;
  }
  if (tid < 112) sA[tid] = ws[WS_A + n * C_ + tid];
  for (int idx = tid; idx < C_ * 12; idx += 256) {
    int i = idx / 12, q = idx - i * 12;
    float4 v = *(const float4*)&xb[(size_t)i * HW_ + 4 * q];
    xT[4 * q + 2][i] = f2bf(v.x);
    xT[4 * q + 3][i] = f2bf(v.y);
    xT[4 * q + 4][i] = f2bf(v.z);
    xT[4 * q + 5][i] = f2bf(v.w);
  }
  __syncthreads();
  const unsigned short* wp = (const unsigned short*)(ws + WS_WPACK);
  const unsigned short* gb = (const unsigned short*)(ws + WS_GBF) + (size_t)n * C_ * 128;

  unsigned short tv[6][4];
#pragma unroll
  for (int j = 0; j < 6; ++j) {
    int t = wv + 4 * j;
    if (t < 21) {
      int m = t / 3, nt = t - 3 * m;
      int o0 = m * 16, w0 = nt * 16;
      f32x4 acc = {0.f, 0.f, 0.f, 0.f};
#pragma unroll
      for (int kx = 0; kx < 3; ++kx) {
        const unsigned short* arow = wp + ((kx * 112 + o0 + lr) * 128 + 8 * lg);
        const unsigned short* brow = &xT[w0 + lr + 2 * kx][8 * lg];
#pragma unroll
        for (int ks = 0; ks < 4; ++ks) {
          bfrag a = *(const bfrag*)(arow + 32 * ks);
          bfrag b = *(const bfrag*)(brow + 32 * ks);
          acc = __builtin_amdgcn_mfma_f32_16x16x32_bf16(a, b, acc, 0, 0, 0);
        }
      }
#pragma unroll
      for (int e = 0; e < 4; ++e) {
        float xv = bf2f(xT[w0 + lr + 2][o0 + 4 * lg + e]);
        tv[j][e] = f2bf(fmaxf(-acc[e], xv));  // t13 = max(-conv, x)
      }
    }
  }
  __syncthreads();
#pragma unroll
  for (int j = 0; j < 6; ++j) {
    int t = wv + 4 * j;
    if (t < 21) {
      int m = t / 3, nt = t - 3 * m;
      int o0 = m * 16, w0 = nt * 16;
      unsigned pk0 = (unsigned)tv[j][0] | ((unsigned)tv[j][1] << 16);
      unsigned pk1 = (unsigned)tv[j][2] | ((unsigned)tv[j][3] << 16);
      *(unsigned*)&xT[w0 + lr + 2][o0 + 4 * lg] = pk0;
      *(unsigned*)&xT[w0 + lr + 2][o0 + 4 * lg + 2] = pk1;
    }
  }
  __syncthreads();
#pragma unroll
  for (int j = 0; j < 6; ++j) {
    int t = wv + 4 * j;
    if (t < 21) {
      int m = t / 3, nt = t - 3 * m;
      int c0 = m * 16, w0 = nt * 16;
      f32x4 acc = {0.f, 0.f, 0.f, 0.f};
      const unsigned short* arow = gb + ((c0 + lr) * 128 + 8 * lg);
      const unsigned short* brow = &xT[w0 + lr + 2][8 * lg];
#pragma unroll
      for (int ks = 0; ks < 4; ++ks) {
        bfrag a = *(const bfrag*)(arow + 32 * ks);
        bfrag b = *(const bfrag*)(brow + 32 * ks);
        acc = __builtin_amdgcn_mfma_f32_16x16x32_bf16(a, b, acc, 0, 0, 0);
      }
#pragma unroll
      for (int e = 0; e < 4; ++e) {
        int c = c0 + 4 * lg + e;
        out[((size_t)n * C_ + c) * HW_ + h * W_ + w0 + lr] = sA[c] - acc[e];
      }
    }
  }
}

// ---------------------------------------------------------------------------
extern "C" void kernel_launch(void* const* d_in, const int* in_sizes, int n_in,
                              void* d_out, int out_size, void* d_ws, size_t ws_size,
                              hipStream_t stream) {
  const float* x = (const float*)d_in[0];
  const float* p7 = (const float*)d_in[1];
  // d_in[2] (p8_w) cancels algebraically: t10 = t8 - (x + t8) = -x
  const float* p19 = (const float*)d_in[3];
  const float* cw = (const float*)d_in[4];
  float* ws = (float*)d_ws;
  float* out = (float*)d_out;

  ath_gram<<<NKS * N_ + 42, 256, 0, stream>>>(x, cw, ws);
  ath_t7n<<<N_, 128, 0, stream>>>(p7, ws);
  ath_assemble<<<224, 256, 0, stream>>>(x, p19, ws);
  ath_fused<<<dim3(H_, N_), 256, 0, stream>>>(x, ws, out);
}

// Round 10
// 67.066 us; speedup vs baseline: 1.1616x; 1.1616x over previous
//
#include <hip/hip_runtime.h>

typedef __attribute__((ext_vector_type(8))) short bfrag;   // 8 bf16 = 4 VGPR
typedef __attribute__((ext_vector_type(4))) float f32x4;

namespace {
constexpr int N_ = 16, C_ = 112, H_ = 48, W_ = 48, HW_ = 2304;
constexpr int NKS = 18;  // K-slices of 128 (18*128 = 2304)
// ws float offsets
constexpr int WS_T7 = 0;          // 768
constexpr int WS_T17 = 768;       // 112
constexpr int WS_A = 1024;        // 1792 -> 2816
constexpr int WS_MX = 4096;       // 16*2304 = 36864 -> 40960
constexpr int WS_WPACK = 40960;   // 3*112*128 bf16 = 21504 f -> 62464
constexpr int WS_GBF = 62464;     // 16*112*128 bf16 = 114688 f -> 177152
constexpr int WS_SPART = 177152;  // 18*16*112*128 f32 = 4128768 -> 4305920 (17.2 MB)
}

__device__ __forceinline__ float f4e(const float4& v, int e) {
  return e == 0 ? v.x : e == 1 ? v.y : e == 2 ? v.z : v.w;
}
__device__ __forceinline__ unsigned short f2bf(float f) {  // RNE
  unsigned u = __float_as_uint(f);
  return (unsigned short)((u + 0x7FFFu + ((u >> 16) & 1u)) >> 16);
}
__device__ __forceinline__ float bf2f(unsigned short s) {
  return __uint_as_float(((unsigned)s) << 16);
}

// ---------------------------------------------------------------------------
// K0: MX colsum (per (n,ks) slice) + wpack tail.
__global__ __launch_bounds__(256) void ath_pre(const float* __restrict__ x,
                                               const float* __restrict__ cw,
                                               float* __restrict__ ws) {
  const int bid = blockIdx.x;
  const int tid = threadIdx.x;
  if (bid >= NKS * N_) {  // ---- wpack tail: bf16 [kx][o][i pad 128]
    int idx = (bid - NKS * N_) * 256 + tid;
    if (idx < 3 * 112 * 32) {
      int kx = idx / (112 * 32);
      int r = idx - kx * 112 * 32;
      int o = r >> 5;
      int i0 = (r & 31) * 4;
      unsigned short v[4];
#pragma unroll
      for (int e = 0; e < 4; ++e) {
        int i = i0 + e;
        v[e] = (i < 112) ? f2bf(cw[o * 336 + i * 3 + kx]) : (unsigned short)0;
      }
      unsigned short* wp = (unsigned short*)(ws + WS_WPACK);
      *(ushort4*)&wp[(kx * 112 + o) * 128 + i0] = make_ushort4(v[0], v[1], v[2], v[3]);
    }
    return;
  }
  const int ks = bid % NKS, n = bid / NKS;
  const int k0 = ks * 128;
  __shared__ float4 csred[256];
  const int kq = tid & 31, cg = tid >> 5;
  float4 cs = make_float4(0.f, 0.f, 0.f, 0.f);
#pragma unroll
  for (int r = 0; r < 14; ++r) {
    const int c = cg + 8 * r;
    float4 v = *(const float4*)&x[((size_t)n * C_ + c) * HW_ + k0 + 4 * kq];
    cs.x += v.x; cs.y += v.y; cs.z += v.z; cs.w += v.w;
  }
  csred[tid] = cs;
  __syncthreads();
  if (tid < 32) {
    float4 s = csred[tid];
#pragma unroll
    for (int g = 1; g < 8; ++g) {
      float4 t = csred[tid + 32 * g];
      s.x += t.x; s.y += t.y; s.z += t.z; s.w += t.w;
    }
    *(float4*)&ws[WS_MX + n * HW_ + k0 + 4 * tid] = s;
  }
}

// ---------------------------------------------------------------------------
// K1: per-n t7 (value from mean-row h' lands at (h'+2)%48; S3=+1,S6=+1) + t17.
__global__ __launch_bounds__(64) void ath_t7n(const float* __restrict__ p7,
                                              float* __restrict__ ws) {
  const int n = blockIdx.x;
  const int tid = threadIdx.x;
  __shared__ __align__(16) float mxs[2304];
  __shared__ float t7s[48];
  for (int idx = tid; idx < 576; idx += 64) {
    float4 v = *(const float4*)&ws[WS_MX + n * HW_ + 4 * idx];
    v.x *= (1.0f / 112.0f); v.y *= (1.0f / 112.0f);
    v.z *= (1.0f / 112.0f); v.w *= (1.0f / 112.0f);
    *(float4*)&mxs[4 * idx] = v;
  }
  __syncthreads();
  if (tid < 48) {
    float s = 0.f;
    for (int k = 0; k < 3; ++k)
      for (int wp = 0; wp < W_; ++wp) {
        int j = 3 * k + wp - 3;
        if (j >= 0 && j < W_) s += mxs[tid * 48 + j] * p7[k * W_ + wp];
      }
    const int hd = (tid + 2) % 48;
    t7s[hd] = s;
    ws[WS_T7 + n * H_ + hd] = s;
  }
  __syncthreads();
  if (tid < 7) {
    float s = 0.f;
    for (int hh = 0; hh < 48; ++hh) {
      int j = 2 * tid + hh - 6;
      if (j >= 0 && j < 48) s += fabsf(t7s[j]);
    }
    ws[WS_T17 + n * 7 + tid] = s * (1.0f / 48.0f);
  }
}

// ---------------------------------------------------------------------------
// K2: Gram via MFMA with st17-augmented A operand and virtual t7 B-row.
// S'[c,i] = sum_p (x[c,p]+st17[(c+p)%7]) * x[i,p]  (i<112)
// S'[c,112] = A1[c]+A2[c%7]  -> A' (virtual row b[112,p]=t7[p/48])
// grid NKS*N_, 256 threads; 7x8=56 16x16 tiles, 14/wave.
__global__ __launch_bounds__(256) void ath_gram(const float* __restrict__ x,
                                                float* __restrict__ ws) {
  const int bid = blockIdx.x;
  const int tid = threadIdx.x;
  const int ks = bid % NKS, n = bid / NKS;
  const int k0 = ks * 128;
  const int lane = tid & 63, wv = tid >> 6;
  const int lr = lane & 15, lg = lane >> 4;
  __shared__ __align__(16) unsigned short As[112][136];
  __shared__ __align__(16) unsigned short Bs[112][136];
  __shared__ __align__(16) unsigned short t7r[136];
  __shared__ float s17[7];
  if (tid < 7) s17[tid] = ws[WS_T17 + n * 7 + tid];
  if (tid < 128) t7r[tid] = f2bf(ws[WS_T7 + n * H_ + (k0 + tid) / 48]);
  if (tid >= 128 && tid < 136) t7r[tid] = 0;
  __syncthreads();
  const int kq = tid & 31, cg = tid >> 5;
  const int base7 = (k0 + 4 * kq) % 7;
#pragma unroll
  for (int r = 0; r < 14; ++r) {
    const int c = cg + 8 * r;
    float4 v = *(const float4*)&x[((size_t)n * C_ + c) * HW_ + k0 + 4 * kq];
    int cls0 = (base7 + c) % 7;
    unsigned short a4[4], b4[4];
#pragma unroll
    for (int e = 0; e < 4; ++e) {
      float xv = f4e(v, e);
      int cl = cls0 + e;
      cl = (cl >= 7) ? cl - 7 : cl;
      b4[e] = f2bf(xv);
      a4[e] = f2bf(xv + s17[cl]);
    }
    *(ushort4*)&Bs[c][4 * kq] = make_ushort4(b4[0], b4[1], b4[2], b4[3]);
    *(ushort4*)&As[c][4 * kq] = make_ushort4(a4[0], a4[1], a4[2], a4[3]);
  }
  __syncthreads();
  const bfrag zero8 = {0, 0, 0, 0, 0, 0, 0, 0};
  f32x4 acc[14];
#pragma unroll
  for (int j = 0; j < 14; ++j) acc[j] = (f32x4){0.f, 0.f, 0.f, 0.f};
#pragma unroll
  for (int j = 0; j < 14; ++j) {
    const int t = wv + 4 * j;  // 0..55
    const int tc = t >> 3, ti = t & 7;
#pragma unroll
    for (int kb = 0; kb < 4; ++kb) {
      bfrag a = *(const bfrag*)&As[16 * tc + lr][8 * lg + 32 * kb];
      bfrag b;
      if (ti < 7) {
        b = *(const bfrag*)&Bs[16 * ti + lr][8 * lg + 32 * kb];
      } else {
        bfrag tb = *(const bfrag*)&t7r[8 * lg + 32 * kb];
        b = (lr == 0) ? tb : zero8;
      }
      acc[j] = __builtin_amdgcn_mfma_f32_16x16x32_bf16(a, b, acc[j], 0, 0, 0);
    }
  }
  float* sp = ws + WS_SPART + (size_t)(n * NKS + ks) * 14336;
#pragma unroll
  for (int j = 0; j < 14; ++j) {
    const int t = wv + 4 * j;
    const int tc = t >> 3, ti = t & 7;
#pragma unroll
    for (int e = 0; e < 4; ++e)
      sp[(16 * tc + 4 * lg + e) * 128 + 16 * ti + lr] = acc[j][e];
  }
}

// ---------------------------------------------------------------------------
// K3: reduce SPART -> Gbf (bf16, cols>=112 zero) + A'. grid N*28, 128 thr.
__global__ __launch_bounds__(128) void ath_assemble(const float* __restrict__ p19,
                                                    float* __restrict__ ws) {
  const int bid = blockIdx.x;
  const int n = bid / 28, g = bid % 28;
  const int tid = threadIdx.x;
  const int cloc = tid >> 5, q = tid & 31;
  const int c = 4 * g + cloc;
  const int i0 = 4 * q;
  float4 s = make_float4(0.f, 0.f, 0.f, 0.f);
#pragma unroll
  for (int ks = 0; ks < NKS; ++ks) {
    float4 t = *(const float4*)&ws[WS_SPART + (size_t)(n * NKS + ks) * 14336 + c * 128 + i0];
    s.x += t.x; s.y += t.y; s.z += t.z; s.w += t.w;
  }
  unsigned short* gb = (unsigned short*)(ws + WS_GBF);
  if (i0 < 112) {
    const float scale = 1.0f / (48.0f * sqrtf(112.0f));
    const float pc = p19[c];
    *(ushort4*)&gb[((size_t)n * C_ + c) * 128 + i0] =
        make_ushort4(f2bf(pc * s.x * scale), f2bf(pc * s.y * scale),
                     f2bf(pc * s.z * scale), f2bf(pc * s.w * scale));
  } else {
    *(ushort4*)&gb[((size_t)n * C_ + c) * 128 + i0] = make_ushort4(0, 0, 0, 0);
    if (i0 == 112) ws[WS_A + n * C_ + c] = p19[c] * s.x * (2.0f / 48.0f);
  }
}

// ---------------------------------------------------------------------------
// K4 fused via MFMA. xT[52][136] bf16: row r = w+2 (rows 0,1,50,51 zero);
// cols 112..135 zero (K-pad). conv = 3 shift-GEMMs vs wpack; t13 in-place;
// final GEMM vs Gbf. 21 16x16 tiles round-robin over 4 waves.
__global__ __launch_bounds__(256) void ath_fused(const float* __restrict__ x,
                                                 const float* __restrict__ ws,
                                                 float* __restrict__ out) {
  const int h = blockIdx.x, n = blockIdx.y;
  const int tid = threadIdx.x;
  const int lane = tid & 63, wv = tid >> 6;
  const int lr = lane & 15, lg = lane >> 4;
  __shared__ __align__(16) unsigned short xT[52][136];
  __shared__ float sA[112];
  const float* xb = x + (size_t)n * C_ * HW_ + h * W_;
  for (int idx = tid; idx < 52 * 24; idx += 256) {
    int r2 = idx / 24, cc = 112 + idx % 24;
    xT[r2][cc] = 0;
  }
  for (int idx = tid; idx < 4 * 112; idx += 256) {
    int rr = idx / 112;
    int r2 = (rr < 2) ? rr : 48 + rr;
    xT[r2][idx % 112] = 0;
  }
  if (tid < 112) sA[tid] = ws[WS_A + n * C_ + tid];
  for (int idx = tid; idx < C_ * 12; idx += 256) {
    int i = idx / 12, q = idx - i * 12;
    float4 v = *(const float4*)&xb[(size_t)i * HW_ + 4 * q];
    xT[4 * q + 2][i] = f2bf(v.x);
    xT[4 * q + 3][i] = f2bf(v.y);
    xT[4 * q + 4][i] = f2bf(v.z);
    xT[4 * q + 5][i] = f2bf(v.w);
  }
  __syncthreads();
  const unsigned short* wp = (const unsigned short*)(ws + WS_WPACK);
  const unsigned short* gb = (const unsigned short*)(ws + WS_GBF) + (size_t)n * C_ * 128;

  unsigned short tv[6][4];
#pragma unroll
  for (int j = 0; j < 6; ++j) {
    int t = wv + 4 * j;
    if (t < 21) {
      int m = t / 3, nt = t - 3 * m;
      int o0 = m * 16, w0 = nt * 16;
      f32x4 acc = {0.f, 0.f, 0.f, 0.f};
#pragma unroll
      for (int kx = 0; kx < 3; ++kx) {
        const unsigned short* arow = wp + ((kx * 112 + o0 + lr) * 128 + 8 * lg);
        const unsigned short* brow = &xT[w0 + lr + 2 * kx][8 * lg];
#pragma unroll
        for (int ks = 0; ks < 4; ++ks) {
          bfrag a = *(const bfrag*)(arow + 32 * ks);
          bfrag b = *(const bfrag*)(brow + 32 * ks);
          acc = __builtin_amdgcn_mfma_f32_16x16x32_bf16(a, b, acc, 0, 0, 0);
        }
      }
#pragma unroll
      for (int e = 0; e < 4; ++e) {
        float xv = bf2f(xT[w0 + lr + 2][o0 + 4 * lg + e]);
        tv[j][e] = f2bf(fmaxf(-acc[e], xv));  // t13 = max(-conv, x)
      }
    }
  }
  __syncthreads();
#pragma unroll
  for (int j = 0; j < 6; ++j) {
    int t = wv + 4 * j;
    if (t < 21) {
      int m = t / 3, nt = t - 3 * m;
      int o0 = m * 16, w0 = nt * 16;
      unsigned pk0 = (unsigned)tv[j][0] | ((unsigned)tv[j][1] << 16);
      unsigned pk1 = (unsigned)tv[j][2] | ((unsigned)tv[j][3] << 16);
      *(unsigned*)&xT[w0 + lr + 2][o0 + 4 * lg] = pk0;
      *(unsigned*)&xT[w0 + lr + 2][o0 + 4 * lg + 2] = pk1;
    }
  }
  __syncthreads();
#pragma unroll
  for (int j = 0; j < 6; ++j) {
    int t = wv + 4 * j;
    if (t < 21) {
      int m = t / 3, nt = t - 3 * m;
      int c0 = m * 16, w0 = nt * 16;
      f32x4 acc = {0.f, 0.f, 0.f, 0.f};
      const unsigned short* arow = gb + ((c0 + lr) * 128 + 8 * lg);
      const unsigned short* brow = &xT[w0 + lr + 2][8 * lg];
#pragma unroll
      for (int ks = 0; ks < 4; ++ks) {
        bfrag a = *(const bfrag*)(arow + 32 * ks);
        bfrag b = *(const bfrag*)(brow + 32 * ks);
        acc = __builtin_amdgcn_mfma_f32_16x16x32_bf16(a, b, acc, 0, 0, 0);
      }
#pragma unroll
      for (int e = 0; e < 4; ++e) {
        int c = c0 + 4 * lg + e;
        out[((size_t)n * C_ + c) * HW_ + h * W_ + w0 + lr] = sA[c] - acc[e];
      }
    }
  }
}

// ---------------------------------------------------------------------------
extern "C" void kernel_launch(void* const* d_in, const int* in_sizes, int n_in,
                              void* d_out, int out_size, void* d_ws, size_t ws_size,
                              hipStream_t stream) {
  const float* x = (const float*)d_in[0];
  const float* p7 = (const float*)d_in[1];
  // d_in[2] (p8_w) cancels algebraically: t10 = t8 - (x + t8) = -x
  const float* p19 = (const float*)d_in[3];
  const float* cw = (const float*)d_in[4];
  float* ws = (float*)d_ws;
  float* out = (float*)d_out;

  ath_pre<<<NKS * N_ + 42, 256, 0, stream>>>(x, cw, ws);
  ath_t7n<<<N_, 64, 0, stream>>>(p7, ws);
  ath_gram<<<NKS * N_, 256, 0, stream>>>(x, ws);
  ath_assemble<<<N_ * 28, 128, 0, stream>>>(p19, ws);
  ath_fused<<<dim3(H_, N_), 256, 0, stream>>>(x, ws, out);
}

// Round 11
// 61.947 us; speedup vs baseline: 1.2576x; 1.0826x over previous
//
#include <hip/hip_runtime.h>

typedef __attribute__((ext_vector_type(8))) short bfrag;   // 8 bf16 = 4 VGPR
typedef __attribute__((ext_vector_type(4))) float f32x4;

namespace {
constexpr int N_ = 16, C_ = 112, H_ = 48, W_ = 48, HW_ = 2304;
constexpr int NKS = 18;  // K-slices of 128 (18*128 = 2304)
// ws float offsets
constexpr int WS_T7 = 0;          // 768
constexpr int WS_A = 1024;        // 1792 -> 2816
constexpr int WS_WPACK = 40960;   // 3*112*128 bf16 = 21504 f -> 62464
constexpr int WS_GBF = 62464;     // 16*112*128 bf16 = 114688 f -> 177152
constexpr int WS_SPART = 177152;  // 18*16*112*128 f32 = 4128768 -> 4305920 (17.2 MB)
}

__device__ __forceinline__ float f4e(const float4& v, int e) {
  return e == 0 ? v.x : e == 1 ? v.y : e == 2 ? v.z : v.w;
}
__device__ __forceinline__ unsigned short f2bf(float f) {  // RNE
  unsigned u = __float_as_uint(f);
  return (unsigned short)((u + 0x7FFFu + ((u >> 16) & 1u)) >> 16);
}
__device__ __forceinline__ float bf2f(unsigned short s) {
  return __uint_as_float(((unsigned)s) << 16);
}

// ---------------------------------------------------------------------------
// K1: t7 directly as a 48-tap projection of x rows.
// t7[n,h'] = (1/112) sum_c dot(x[n,c,h',:], q), q[j] = sum_k p7[k][j+3-3k];
// value lands at (h'+2)%48 (S3=+1,S6=+1 rolls compound to +2).
// grid (48, 16), 64 threads.
__global__ __launch_bounds__(64) void ath_t7(const float* __restrict__ x,
                                             const float* __restrict__ p7,
                                             float* __restrict__ ws) {
  const int h = blockIdx.x, n = blockIdx.y;
  const int tid = threadIdx.x;
  __shared__ float q[48];
  if (tid < 48) {
    float s = 0.f;
#pragma unroll
    for (int k = 0; k < 3; ++k) {
      int wp = tid + 3 - 3 * k;
      if (wp >= 0 && wp < 48) s += p7[k * 48 + wp];
    }
    q[tid] = s;
  }
  __syncthreads();
  float d = 0.f;
  {
    const float4* x4 = (const float4*)(x + ((size_t)n * C_ + tid) * HW_ + h * W_);
#pragma unroll
    for (int t = 0; t < 12; ++t) {
      float4 v = x4[t];
      d += v.x * q[4 * t] + v.y * q[4 * t + 1] + v.z * q[4 * t + 2] + v.w * q[4 * t + 3];
    }
  }
  if (tid < 48) {
    const float4* x4 = (const float4*)(x + ((size_t)n * C_ + 64 + tid) * HW_ + h * W_);
#pragma unroll
    for (int t = 0; t < 12; ++t) {
      float4 v = x4[t];
      d += v.x * q[4 * t] + v.y * q[4 * t + 1] + v.z * q[4 * t + 2] + v.w * q[4 * t + 3];
    }
  }
#pragma unroll
  for (int off = 32; off >= 1; off >>= 1) d += __shfl_xor(d, off);
  if (tid == 0) ws[WS_T7 + n * H_ + (h + 2) % 48] = d * (1.0f / 112.0f);
}

// ---------------------------------------------------------------------------
// K2: Gram via MFMA, st17-augmented A (LDS) x raw-x B (direct global frags),
// virtual t7 B-row for A'. Block = (n, ks, half): half owns ti = wv + 4*half.
// t17 recomputed per block from t7 (cheap). Tail blocks: wpack.
// grid 576 + 42, 256 threads.
__global__ __launch_bounds__(256) void ath_gram(const float* __restrict__ x,
                                                const float* __restrict__ cw,
                                                float* __restrict__ ws) {
  const int bid = blockIdx.x;
  const int tid = threadIdx.x;
  if (bid >= 2 * NKS * N_) {  // ---- wpack tail: bf16 [kx][o][i pad 128]
    int idx = (bid - 2 * NKS * N_) * 256 + tid;
    if (idx < 3 * 112 * 32) {
      int kx = idx / (112 * 32);
      int r = idx - kx * 112 * 32;
      int o = r >> 5;
      int i0 = (r & 31) * 4;
      unsigned short v[4];
#pragma unroll
      for (int e = 0; e < 4; ++e) {
        int i = i0 + e;
        v[e] = (i < 112) ? f2bf(cw[o * 336 + i * 3 + kx]) : (unsigned short)0;
      }
      unsigned short* wp = (unsigned short*)(ws + WS_WPACK);
      *(ushort4*)&wp[(kx * 112 + o) * 128 + i0] = make_ushort4(v[0], v[1], v[2], v[3]);
    }
    return;
  }
  const int half = bid & 1;
  const int ks = (bid >> 1) % NKS;
  const int n = bid / (2 * NKS);
  const int k0 = ks * 128;
  const int lane = tid & 63, wv = tid >> 6;
  const int lr = lane & 15, lg = lane >> 4;
  __shared__ __align__(16) unsigned short As[112][136];
  __shared__ __align__(16) unsigned short t7r[136];
  __shared__ float t7s[48];
  __shared__ float s17[8];
  if (tid < 48) t7s[tid] = ws[WS_T7 + n * H_ + tid];
  __syncthreads();
  if (tid < 7) {  // t17[kk] = (1/48) sum_h |t7pad[2kk+h-6]|
    float s = 0.f;
    for (int hh = 0; hh < 48; ++hh) {
      int j = 2 * tid + hh - 6;
      if (j >= 0 && j < 48) s += fabsf(t7s[j]);
    }
    s17[tid] = s * (1.0f / 48.0f);
  }
  if (tid >= 64 && tid < 192) t7r[tid - 64] = f2bf(t7s[(k0 + tid - 64) / 48]);
  if (tid >= 192 && tid < 200) t7r[128 + (tid - 192)] = 0;
  __syncthreads();
  // stage augmented A: As[c][p-k0] = bf16(x[c,p] + s17[(c+p)%7])
  const int kq = tid & 31, cg = tid >> 5;
  const int base7 = (k0 + 4 * kq) % 7;
#pragma unroll
  for (int r = 0; r < 14; ++r) {
    const int c = cg + 8 * r;
    float4 v = *(const float4*)&x[((size_t)n * C_ + c) * HW_ + k0 + 4 * kq];
    int cls0 = (base7 + c) % 7;
    unsigned short a4[4];
#pragma unroll
    for (int e = 0; e < 4; ++e) {
      int cl = cls0 + e;
      cl = (cl >= 7) ? cl - 7 : cl;
      a4[e] = f2bf(f4e(v, e) + s17[cl]);
    }
    *(ushort4*)&As[c][4 * kq] = make_ushort4(a4[0], a4[1], a4[2], a4[3]);
  }
  __syncthreads();
  const int ti = wv + 4 * half;  // this wave's output column-group (0..7)
  const bfrag zero8 = {0, 0, 0, 0, 0, 0, 0, 0};
  f32x4 acc[7];
#pragma unroll
  for (int j = 0; j < 7; ++j) acc[j] = (f32x4){0.f, 0.f, 0.f, 0.f};
#pragma unroll
  for (int kb = 0; kb < 4; ++kb) {
    bfrag b;
    if (ti < 7) {
      const float* bp = &x[((size_t)n * C_ + 16 * ti + lr) * HW_ + k0 + 8 * lg + 32 * kb];
      float4 v0 = *(const float4*)bp;
      float4 v1 = *(const float4*)(bp + 4);
      b[0] = (short)f2bf(v0.x); b[1] = (short)f2bf(v0.y);
      b[2] = (short)f2bf(v0.z); b[3] = (short)f2bf(v0.w);
      b[4] = (short)f2bf(v1.x); b[5] = (short)f2bf(v1.y);
      b[6] = (short)f2bf(v1.z); b[7] = (short)f2bf(v1.w);
    } else {
      b = (lr == 0) ? *(const bfrag*)&t7r[8 * lg + 32 * kb] : zero8;
    }
#pragma unroll
    for (int tc = 0; tc < 7; ++tc) {
      bfrag a = *(const bfrag*)&As[16 * tc + lr][8 * lg + 32 * kb];
      acc[tc] = __builtin_amdgcn_mfma_f32_16x16x32_bf16(a, b, acc[tc], 0, 0, 0);
    }
  }
  float* sp = ws + WS_SPART + (size_t)(n * NKS + ks) * 14336;
#pragma unroll
  for (int tc = 0; tc < 7; ++tc)
#pragma unroll
    for (int e = 0; e < 4; ++e)
      sp[(16 * tc + 4 * lg + e) * 128 + 16 * ti + lr] = acc[tc][e];
}

// ---------------------------------------------------------------------------
// K3: reduce SPART -> Gbf (bf16, cols>=112 zero) + A'. grid N*28, 128 thr.
__global__ __launch_bounds__(128) void ath_assemble(const float* __restrict__ p19,
                                                    float* __restrict__ ws) {
  const int bid = blockIdx.x;
  const int n = bid / 28, g = bid % 28;
  const int tid = threadIdx.x;
  const int cloc = tid >> 5, q = tid & 31;
  const int c = 4 * g + cloc;
  const int i0 = 4 * q;
  float4 s = make_float4(0.f, 0.f, 0.f, 0.f);
#pragma unroll
  for (int ks = 0; ks < NKS; ++ks) {
    float4 t = *(const float4*)&ws[WS_SPART + (size_t)(n * NKS + ks) * 14336 + c * 128 + i0];
    s.x += t.x; s.y += t.y; s.z += t.z; s.w += t.w;
  }
  unsigned short* gb = (unsigned short*)(ws + WS_GBF);
  if (i0 < 112) {
    const float scale = 1.0f / (48.0f * sqrtf(112.0f));
    const float pc = p19[c];
    *(ushort4*)&gb[((size_t)n * C_ + c) * 128 + i0] =
        make_ushort4(f2bf(pc * s.x * scale), f2bf(pc * s.y * scale),
                     f2bf(pc * s.z * scale), f2bf(pc * s.w * scale));
  } else {
    *(ushort4*)&gb[((size_t)n * C_ + c) * 128 + i0] = make_ushort4(0, 0, 0, 0);
    if (i0 == 112) ws[WS_A + n * C_ + c] = p19[c] * s.x * (2.0f / 48.0f);
  }
}

// ---------------------------------------------------------------------------
// K4 fused via MFMA. xT[52][136] bf16: row r = w+2 (rows 0,1,50,51 zero);
// cols 112..135 zero (K-pad). conv = 3 shift-GEMMs vs wpack; t13 in-place;
// final GEMM vs Gbf. 21 16x16 tiles round-robin over 4 waves.
__global__ __launch_bounds__(256) void ath_fused(const float* __restrict__ x,
                                                 const float* __restrict__ ws,
                                                 float* __restrict__ out) {
  const int h = blockIdx.x, n = blockIdx.y;
  const int tid = threadIdx.x;
  const int lane = tid & 63, wv = tid >> 6;
  const int lr = lane & 15, lg = lane >> 4;
  __shared__ __align__(16) unsigned short xT[52][136];
  __shared__ float sA[112];
  const float* xb = x + (size_t)n * C_ * HW_ + h * W_;
  for (int idx = tid; idx < 52 * 24; idx += 256) {
    int r2 = idx / 24, cc = 112 + idx % 24;
    xT[r2][cc] = 0;
  }
  for (int idx = tid; idx < 4 * 112; idx += 256) {
    int rr = idx / 112;
    int r2 = (rr < 2) ? rr : 48 + rr;
    xT[r2][idx % 112] = 0;
  }
  if (tid < 112) sA[tid] = ws[WS_A + n * C_ + tid];
  for (int idx = tid; idx < C_ * 12; idx += 256) {
    int i = idx / 12, q = idx - i * 12;
    float4 v = *(const float4*)&xb[(size_t)i * HW_ + 4 * q];
    xT[4 * q + 2][i] = f2bf(v.x);
    xT[4 * q + 3][i] = f2bf(v.y);
    xT[4 * q + 4][i] = f2bf(v.z);
    xT[4 * q + 5][i] = f2bf(v.w);
  }
  __syncthreads();
  const unsigned short* wp = (const unsigned short*)(ws + WS_WPACK);
  const unsigned short* gb = (const unsigned short*)(ws + WS_GBF) + (size_t)n * C_ * 128;

  unsigned short tv[6][4];
#pragma unroll
  for (int j = 0; j < 6; ++j) {
    int t = wv + 4 * j;
    if (t < 21) {
      int m = t / 3, nt = t - 3 * m;
      int o0 = m * 16, w0 = nt * 16;
      f32x4 acc = {0.f, 0.f, 0.f, 0.f};
#pragma unroll
      for (int kx = 0; kx < 3; ++kx) {
        const unsigned short* arow = wp + ((kx * 112 + o0 + lr) * 128 + 8 * lg);
        const unsigned short* brow = &xT[w0 + lr + 2 * kx][8 * lg];
#pragma unroll
        for (int ks = 0; ks < 4; ++ks) {
          bfrag a = *(const bfrag*)(arow + 32 * ks);
          bfrag b = *(const bfrag*)(brow + 32 * ks);
          acc = __builtin_amdgcn_mfma_f32_16x16x32_bf16(a, b, acc, 0, 0, 0);
        }
      }
#pragma unroll
      for (int e = 0; e < 4; ++e) {
        float xv = bf2f(xT[w0 + lr + 2][o0 + 4 * lg + e]);
        tv[j][e] = f2bf(fmaxf(-acc[e], xv));  // t13 = max(-conv, x)
      }
    }
  }
  __syncthreads();
#pragma unroll
  for (int j = 0; j < 6; ++j) {
    int t = wv + 4 * j;
    if (t < 21) {
      int m = t / 3, nt = t - 3 * m;
      int o0 = m * 16, w0 = nt * 16;
      unsigned pk0 = (unsigned)tv[j][0] | ((unsigned)tv[j][1] << 16);
      unsigned pk1 = (unsigned)tv[j][2] | ((unsigned)tv[j][3] << 16);
      *(unsigned*)&xT[w0 + lr + 2][o0 + 4 * lg] = pk0;
      *(unsigned*)&xT[w0 + lr + 2][o0 + 4 * lg + 2] = pk1;
    }
  }
  __syncthreads();
#pragma unroll
  for (int j = 0; j < 6; ++j) {
    int t = wv + 4 * j;
    if (t < 21) {
      int m = t / 3, nt = t - 3 * m;
      int c0 = m * 16, w0 = nt * 16;
      f32x4 acc = {0.f, 0.f, 0.f, 0.f};
      const unsigned short* arow = gb + ((c0 + lr) * 128 + 8 * lg);
      const unsigned short* brow = &xT[w0 + lr + 2][8 * lg];
#pragma unroll
      for (int ks = 0; ks < 4; ++ks) {
        bfrag a = *(const bfrag*)(arow + 32 * ks);
        bfrag b = *(const bfrag*)(brow + 32 * ks);
        acc = __builtin_amdgcn_mfma_f32_16x16x32_bf16(a, b, acc, 0, 0, 0);
      }
#pragma unroll
      for (int e = 0; e < 4; ++e) {
        int c = c0 + 4 * lg + e;
        out[((size_t)n * C_ + c) * HW_ + h * W_ + w0 + lr] = sA[c] - acc[e];
      }
    }
  }
}

// ---------------------------------------------------------------------------
extern "C" void kernel_launch(void* const* d_in, const int* in_sizes, int n_in,
                              void* d_out, int out_size, void* d_ws, size_t ws_size,
                              hipStream_t stream) {
  const float* x = (const float*)d_in[0];
  const float* p7 = (const float*)d_in[1];
  // d_in[2] (p8_w) cancels algebraically: t10 = t8 - (x + t8) = -x
  const float* p19 = (const float*)d_in[3];
  const float* cw = (const float*)d_in[4];
  float* ws = (float*)d_ws;
  float* out = (float*)d_out;

  ath_t7<<<dim3(H_, N_), 64, 0, stream>>>(x, p7, ws);
  ath_gram<<<2 * NKS * N_ + 42, 256, 0, stream>>>(x, cw, ws);
  ath_assemble<<<N_ * 28, 128, 0, stream>>>(p19, ws);
  ath_fused<<<dim3(H_, N_), 256, 0, stream>>>(x, ws, out);
}

// Round 13
// 47.272 us; speedup vs baseline: 1.6480x; 1.3104x over previous
//
#include <hip/hip_runtime.h>

typedef __attribute__((ext_vector_type(8))) short bfrag;   // 8 bf16 = 4 VGPR
typedef __attribute__((ext_vector_type(4))) float f32x4;

namespace {
constexpr int N_ = 16, C_ = 112, H_ = 48, W_ = 48, HW_ = 2304;
constexpr int NKS = 18;  // K-slices of 128 (18*128 = 2304)
// ws float offsets
constexpr int WS_T7 = 0;          // 768
constexpr int WS_A = 1024;        // 1792 -> 2816
constexpr int WS_WPACK = 40960;   // 3*112*128 bf16 = 21504 f -> 62464
constexpr int WS_GBF = 62464;     // 16*112*128 bf16 = 114688 f -> 177152
constexpr int WS_SPART = 177152;  // 18*16*112*128 f32 = 4128768 -> 4305920 (17.2 MB)
}

__device__ __forceinline__ float f4e(const float4& v, int e) {
  return e == 0 ? v.x : e == 1 ? v.y : e == 2 ? v.z : v.w;
}
__device__ __forceinline__ unsigned short f2bf(float f) {  // RNE
  unsigned u = __float_as_uint(f);
  return (unsigned short)((u + 0x7FFFu + ((u >> 16) & 1u)) >> 16);
}
__device__ __forceinline__ float bf2f(unsigned short s) {
  return __uint_as_float(((unsigned)s) << 16);
}

// ---------------------------------------------------------------------------
// K1: t7 directly as a 48-tap projection of x rows.
// t7[n,h'] = (1/112) sum_c dot(x[n,c,h',:], q), q[j] = sum_k p7[k][j+3-3k];
// value lands at (h'+2)%48 (S3=+1,S6=+1 rolls compound to +2).
// grid (48, 16), 64 threads.
__global__ __launch_bounds__(64) void ath_t7(const float* __restrict__ x,
                                             const float* __restrict__ p7,
                                             float* __restrict__ ws) {
  const int h = blockIdx.x, n = blockIdx.y;
  const int tid = threadIdx.x;
  __shared__ float q[48];
  if (tid < 48) {
    float s = 0.f;
#pragma unroll
    for (int k = 0; k < 3; ++k) {
      int wp = tid + 3 - 3 * k;
      if (wp >= 0 && wp < 48) s += p7[k * 48 + wp];
    }
    q[tid] = s;
  }
  __syncthreads();
  float d = 0.f;
  {
    const float4* x4 = (const float4*)(x + ((size_t)n * C_ + tid) * HW_ + h * W_);
#pragma unroll
    for (int t = 0; t < 12; ++t) {
      float4 v = x4[t];
      d += v.x * q[4 * t] + v.y * q[4 * t + 1] + v.z * q[4 * t + 2] + v.w * q[4 * t + 3];
    }
  }
  if (tid < 48) {
    const float4* x4 = (const float4*)(x + ((size_t)n * C_ + 64 + tid) * HW_ + h * W_);
#pragma unroll
    for (int t = 0; t < 12; ++t) {
      float4 v = x4[t];
      d += v.x * q[4 * t] + v.y * q[4 * t + 1] + v.z * q[4 * t + 2] + v.w * q[4 * t + 3];
    }
  }
#pragma unroll
  for (int off = 32; off >= 1; off >>= 1) d += __shfl_xor(d, off);
  if (tid == 0) ws[WS_T7 + n * H_ + (h + 2) % 48] = d * (1.0f / 112.0f);
}

// ---------------------------------------------------------------------------
// K2: Gram via MFMA, st17-augmented A (LDS) x raw-x B (register-prefetched),
// virtual t7 B-row for A'. Block = (n, ks, half): half owns ti = wv + 4*half.
// t17 recomputed per block from t7 (cheap). Tail blocks: wpack.
// grid 576 + 42, 256 threads.
__global__ __launch_bounds__(256) void ath_gram(const float* __restrict__ x,
                                                const float* __restrict__ cw,
                                                float* __restrict__ ws) {
  const int bid = blockIdx.x;
  const int tid = threadIdx.x;
  if (bid >= 2 * NKS * N_) {  // ---- wpack tail: bf16 [kx][o][i pad 128]
    int idx = (bid - 2 * NKS * N_) * 256 + tid;
    if (idx < 3 * 112 * 32) {
      int kx = idx / (112 * 32);
      int r = idx - kx * 112 * 32;
      int o = r >> 5;
      int i0 = (r & 31) * 4;
      unsigned short v[4];
#pragma unroll
      for (int e = 0; e < 4; ++e) {
        int i = i0 + e;
        v[e] = (i < 112) ? f2bf(cw[o * 336 + i * 3 + kx]) : (unsigned short)0;
      }
      unsigned short* wp = (unsigned short*)(ws + WS_WPACK);
      *(ushort4*)&wp[(kx * 112 + o) * 128 + i0] = make_ushort4(v[0], v[1], v[2], v[3]);
    }
    return;
  }
  const int half = bid & 1;
  const int ks = (bid >> 1) % NKS;
  const int n = bid / (2 * NKS);
  const int k0 = ks * 128;
  const int lane = tid & 63, wv = tid >> 6;
  const int lr = lane & 15, lg = lane >> 4;
  __shared__ __align__(16) unsigned short As[112][136];
  __shared__ __align__(16) unsigned short t7r[136];
  __shared__ float t7s[48];
  __shared__ float s17[8];
  if (tid < 48) t7s[tid] = ws[WS_T7 + n * H_ + tid];
  __syncthreads();
  if (tid < 7) {  // t17[kk] = (1/48) sum_h |t7pad[2kk+h-6]|
    float s = 0.f;
    for (int hh = 0; hh < 48; ++hh) {
      int j = 2 * tid + hh - 6;
      if (j >= 0 && j < 48) s += fabsf(t7s[j]);
    }
    s17[tid] = s * (1.0f / 48.0f);
  }
  if (tid >= 64 && tid < 192) t7r[tid - 64] = f2bf(t7s[(k0 + tid - 64) / 48]);
  if (tid >= 192 && tid < 200) t7r[128 + (tid - 192)] = 0;
  // prefetch B fragments into registers (no LDS dependency; overlaps)
  const int ti = wv + 4 * half;  // this wave's output column-group (0..7)
  bfrag breg[4];
  if (ti < 7) {
    const float* bp = &x[((size_t)n * C_ + 16 * ti + lr) * HW_ + k0 + 8 * lg];
#pragma unroll
    for (int kb = 0; kb < 4; ++kb) {
      float4 v0 = *(const float4*)(bp + 32 * kb);
      float4 v1 = *(const float4*)(bp + 32 * kb + 4);
      breg[kb][0] = (short)f2bf(v0.x); breg[kb][1] = (short)f2bf(v0.y);
      breg[kb][2] = (short)f2bf(v0.z); breg[kb][3] = (short)f2bf(v0.w);
      breg[kb][4] = (short)f2bf(v1.x); breg[kb][5] = (short)f2bf(v1.y);
      breg[kb][6] = (short)f2bf(v1.z); breg[kb][7] = (short)f2bf(v1.w);
    }
  }
  __syncthreads();  // s17/t7r visible to ALL waves before A staging reads s17
  // stage augmented A: As[c][p-k0] = bf16(x[c,p] + s17[(c+p)%7])
  const int kq = tid & 31, cg = tid >> 5;
  const int base7 = (k0 + 4 * kq) % 7;
#pragma unroll
  for (int r = 0; r < 14; ++r) {
    const int c = cg + 8 * r;
    float4 v = *(const float4*)&x[((size_t)n * C_ + c) * HW_ + k0 + 4 * kq];
    int cls0 = (base7 + c) % 7;
    unsigned short a4[4];
#pragma unroll
    for (int e = 0; e < 4; ++e) {
      int cl = cls0 + e;
      cl = (cl >= 7) ? cl - 7 : cl;
      a4[e] = f2bf(f4e(v, e) + s17[cl]);
    }
    *(ushort4*)&As[c][4 * kq] = make_ushort4(a4[0], a4[1], a4[2], a4[3]);
  }
  __syncthreads();
  if (ti == 7) {
    const bfrag zero8 = {0, 0, 0, 0, 0, 0, 0, 0};
#pragma unroll
    for (int kb = 0; kb < 4; ++kb)
      breg[kb] = (lr == 0) ? *(const bfrag*)&t7r[8 * lg + 32 * kb] : zero8;
  }
  f32x4 acc[7];
#pragma unroll
  for (int j = 0; j < 7; ++j) acc[j] = (f32x4){0.f, 0.f, 0.f, 0.f};
#pragma unroll
  for (int kb = 0; kb < 4; ++kb) {
#pragma unroll
    for (int tc = 0; tc < 7; ++tc) {
      bfrag a = *(const bfrag*)&As[16 * tc + lr][8 * lg + 32 * kb];
      acc[tc] = __builtin_amdgcn_mfma_f32_16x16x32_bf16(a, breg[kb], acc[tc], 0, 0, 0);
    }
  }
  float* sp = ws + WS_SPART + (size_t)(n * NKS + ks) * 14336;
#pragma unroll
  for (int tc = 0; tc < 7; ++tc)
#pragma unroll
    for (int e = 0; e < 4; ++e)
      sp[(16 * tc + 4 * lg + e) * 128 + 16 * ti + lr] = acc[tc][e];
}

// ---------------------------------------------------------------------------
// K3: reduce SPART -> Gbf (bf16, cols>=112 zero) + A'. grid N*28, 128 thr.
__global__ __launch_bounds__(128) void ath_assemble(const float* __restrict__ p19,
                                                    float* __restrict__ ws) {
  const int bid = blockIdx.x;
  const int n = bid / 28, g = bid % 28;
  const int tid = threadIdx.x;
  const int cloc = tid >> 5, q = tid & 31;
  const int c = 4 * g + cloc;
  const int i0 = 4 * q;
  float4 s = make_float4(0.f, 0.f, 0.f, 0.f);
#pragma unroll
  for (int ks = 0; ks < NKS; ++ks) {
    float4 t = *(const float4*)&ws[WS_SPART + (size_t)(n * NKS + ks) * 14336 + c * 128 + i0];
    s.x += t.x; s.y += t.y; s.z += t.z; s.w += t.w;
  }
  unsigned short* gb = (unsigned short*)(ws + WS_GBF);
  if (i0 < 112) {
    const float scale = 1.0f / (48.0f * sqrtf(112.0f));
    const float pc = p19[c];
    *(ushort4*)&gb[((size_t)n * C_ + c) * 128 + i0] =
        make_ushort4(f2bf(pc * s.x * scale), f2bf(pc * s.y * scale),
                     f2bf(pc * s.z * scale), f2bf(pc * s.w * scale));
  } else {
    *(ushort4*)&gb[((size_t)n * C_ + c) * 128 + i0] = make_ushort4(0, 0, 0, 0);
    if (i0 == 112) ws[WS_A + n * C_ + c] = p19[c] * s.x * (2.0f / 48.0f);
  }
}

// ---------------------------------------------------------------------------
// K4 fused via MFMA, LDS-stationary operands. xT[52][136] bf16 transposed
// x-slab (row r = w+2; rows 0,1,50,51 and cols>=112 zero). buf[112][136]
// holds the current conv-weight kx-slice, then Gbf. conv = kx-outer 3
// shift-GEMMs with persistent accs; t13 in-place into xT; final GEMM vs buf.
// 21 16x16 tiles round-robin over 4 waves. LDS total ~45 KB (3 blocks/CU).
__global__ __launch_bounds__(256) void ath_fused(const float* __restrict__ x,
                                                 const float* __restrict__ ws,
                                                 float* __restrict__ out) {
  const int h = blockIdx.x, n = blockIdx.y;
  const int tid = threadIdx.x;
  const int lane = tid & 63, wv = tid >> 6;
  const int lr = lane & 15, lg = lane >> 4;
  __shared__ __align__(16) unsigned short xT[52][136];
  __shared__ __align__(16) unsigned short buf[112][136];
  __shared__ float sA[112];
  const float* xb = x + (size_t)n * C_ * HW_ + h * W_;
  const unsigned short* wp = (const unsigned short*)(ws + WS_WPACK);
  const unsigned short* gb = (const unsigned short*)(ws + WS_GBF) + (size_t)n * C_ * 128;
  // zero pads
  for (int idx = tid; idx < 52 * 24; idx += 256) {
    int r2 = idx / 24, cc = 112 + idx % 24;
    xT[r2][cc] = 0;
  }
  for (int idx = tid; idx < 4 * 112; idx += 256) {
    int rr = idx / 112;
    int r2 = (rr < 2) ? rr : 48 + rr;
    xT[r2][idx % 112] = 0;
  }
  if (tid < 112) sA[tid] = ws[WS_A + n * C_ + tid];
  // stage x -> xT bf16 (transpose, packed 2-channel u32 writes)
  for (int idx = tid; idx < 672; idx += 256) {
    int i2 = idx / 12, q = idx - i2 * 12;
    float4 a = *(const float4*)&xb[(size_t)(2 * i2) * HW_ + 4 * q];
    float4 b = *(const float4*)&xb[(size_t)(2 * i2 + 1) * HW_ + 4 * q];
#pragma unroll
    for (int e = 0; e < 4; ++e) {
      unsigned pk = (unsigned)f2bf(f4e(a, e)) | ((unsigned)f2bf(f4e(b, e)) << 16);
      *(unsigned*)&xT[4 * q + 2 + e][2 * i2] = pk;
    }
  }
  // stage wp slice 0 into buf
  for (int idx = tid; idx < 1792; idx += 256) {
    int row = idx >> 4, cq = idx & 15;
    *(float4*)&buf[row][cq * 8] = *(const float4*)&wp[(size_t)row * 128 + cq * 8];
  }
  __syncthreads();

  // ---- conv phase, kx-outer, accs persistent
  f32x4 acc[6];
#pragma unroll
  for (int j = 0; j < 6; ++j) acc[j] = (f32x4){0.f, 0.f, 0.f, 0.f};
  for (int kx = 0; kx < 3; ++kx) {
    if (kx) {
      __syncthreads();  // drain buf reads from previous kx
      for (int idx = tid; idx < 1792; idx += 256) {
        int row = idx >> 4, cq = idx & 15;
        *(float4*)&buf[row][cq * 8] =
            *(const float4*)&wp[(size_t)(kx * 112 + row) * 128 + cq * 8];
      }
      __syncthreads();
    }
#pragma unroll
    for (int j = 0; j < 6; ++j) {
      int t = wv + 4 * j;
      if (t < 21) {
        int m = t / 3, nt = t - 3 * m;
        int o0 = m * 16, w0 = nt * 16;
#pragma unroll
        for (int kb = 0; kb < 4; ++kb) {
          bfrag a = *(const bfrag*)&buf[o0 + lr][8 * lg + 32 * kb];
          bfrag b = *(const bfrag*)&xT[w0 + lr + 2 * kx][8 * lg + 32 * kb];
          acc[j] = __builtin_amdgcn_mfma_f32_16x16x32_bf16(a, b, acc[j], 0, 0, 0);
        }
      }
    }
  }
  // t13 = max(-conv, x)
  unsigned short tv[6][4];
#pragma unroll
  for (int j = 0; j < 6; ++j) {
    int t = wv + 4 * j;
    if (t < 21) {
      int m = t / 3, nt = t - 3 * m;
      int o0 = m * 16, w0 = nt * 16;
#pragma unroll
      for (int e = 0; e < 4; ++e) {
        float xv = bf2f(xT[w0 + lr + 2][o0 + 4 * lg + e]);
        tv[j][e] = f2bf(fmaxf(-acc[j][e], xv));
      }
    }
  }
  __syncthreads();  // all conv reads of xT/buf complete
  // write t13 into xT; stage Gbf into buf
#pragma unroll
  for (int j = 0; j < 6; ++j) {
    int t = wv + 4 * j;
    if (t < 21) {
      int m = t / 3, nt = t - 3 * m;
      int o0 = m * 16, w0 = nt * 16;
      unsigned pk0 = (unsigned)tv[j][0] | ((unsigned)tv[j][1] << 16);
      unsigned pk1 = (unsigned)tv[j][2] | ((unsigned)tv[j][3] << 16);
      *(unsigned*)&xT[w0 + lr + 2][o0 + 4 * lg] = pk0;
      *(unsigned*)&xT[w0 + lr + 2][o0 + 4 * lg + 2] = pk1;
    }
  }
  for (int idx = tid; idx < 1792; idx += 256) {
    int row = idx >> 4, cq = idx & 15;
    *(float4*)&buf[row][cq * 8] = *(const float4*)&gb[(size_t)row * 128 + cq * 8];
  }
  __syncthreads();  // t13 + Gbf visible

  // ---- final GEMM: out[c][w] = A'[c] - sum_i G'[c][i] * t13[i][w]
#pragma unroll
  for (int j = 0; j < 6; ++j) {
    int t = wv + 4 * j;
    if (t < 21) {
      int m = t / 3, nt = t - 3 * m;
      int c0 = m * 16, w0 = nt * 16;
      f32x4 acc2 = {0.f, 0.f, 0.f, 0.f};
#pragma unroll
      for (int kb = 0; kb < 4; ++kb) {
        bfrag a = *(const bfrag*)&buf[c0 + lr][8 * lg + 32 * kb];
        bfrag b = *(const bfrag*)&xT[w0 + lr + 2][8 * lg + 32 * kb];
        acc2 = __builtin_amdgcn_mfma_f32_16x16x32_bf16(a, b, acc2, 0, 0, 0);
      }
#pragma unroll
      for (int e = 0; e < 4; ++e) {
        int c = c0 + 4 * lg + e;
        out[((size_t)n * C_ + c) * HW_ + h * W_ + w0 + lr] = sA[c] - acc2[e];
      }
    }
  }
}

// ---------------------------------------------------------------------------
extern "C" void kernel_launch(void* const* d_in, const int* in_sizes, int n_in,
                              void* d_out, int out_size, void* d_ws, size_t ws_size,
                              hipStream_t stream) {
  const float* x = (const float*)d_in[0];
  const float* p7 = (const float*)d_in[1];
  // d_in[2] (p8_w) cancels algebraically: t10 = t8 - (x + t8) = -x
  const float* p19 = (const float*)d_in[3];
  const float* cw = (const float*)d_in[4];
  float* ws = (float*)d_ws;
  float* out = (float*)d_out;

  ath_t7<<<dim3(H_, N_), 64, 0, stream>>>(x, p7, ws);
  ath_gram<<<2 * NKS * N_ + 42, 256, 0, stream>>>(x, cw, ws);
  ath_assemble<<<N_ * 28, 128, 0, stream>>>(p19, ws);
  ath_fused<<<dim3(H_, N_), 256, 0, stream>>>(x, ws, out);
}